// Round 2
// baseline (375.580 us; speedup 1.0000x reference)
//
#include <hip/hip_runtime.h>

// (B,C,D,H,W) = (2,64,32,64,64), R=2, NCH=125
#define B_ 2
#define C_ 64
#define D_ 32
#define H_ 64
#define W_ 64
#define NCH 125
#define HW_ 4096
#define DHW_ 131072
#define CDHW_ 8388608

// x2 tile per wave: 8 rows, ROW STRIDE 65 dwords (odd -> conflict-free banks:
// bank = (row + col) mod 32 is ~bijective over the 64 lanes for every LDS
// instruction; the old stride-64 layout was an 8-way conflict on every read).
// Reg-staged (global_load_dwordx4 -> ds_write) because global_load_lds forces
// a linear stride-64 dest. 2 buffers/wave, global prefetch distance 2.
// ORDERING: ds_write(slab c+1, iter c) -> ds_read(slab c+1, iter c+1) is
// fenced with s_waitcnt lgkmcnt(0) + sched_barrier(0) after each staging
// block -- do NOT rely on implicit same-wave DS pipe ordering (the previous
// unfenced version showed timing-dependent corruption under graph replay).
// NOTE: stride 65 means odd rows are only 4B-aligned -> ALL LDS access is
// scalar float (compiler merges to ds_read2_b32 / ds_write2_b32, 4B-safe).
#define RSTRIDE 65
#define TBUF (8 * RSTRIDE)          // 520 dwords per buffer
#define WREG (2 * TBUF)             // 1040 dwords per wave (2 buffers)

__device__ __attribute__((aligned(16))) const float g_zero[4] = {0.f, 0.f, 0.f, 0.f};

__device__ __forceinline__ void lds_fence() {
    asm volatile("s_waitcnt lgkmcnt(0)" ::: "memory");
    __builtin_amdgcn_sched_barrier(0);
}

// Live offsets form an L: s=i+j in [-4..4], last-write winner is
//   s<=0 -> (i,j)=(s+2,-2): rows y-2..y+2, cols x+2..x+5  (acc[4-k])
//   s>=0 -> (i,j)=(2,s-2) : row y-2, cols x+2-s           (acc[s+4])
// ch=(5s+h) mod 125 -> live {0..22}u{103..124}; 23..102 identically zero.
__global__ __launch_bounds__(128, 5) void cv_all(const float* __restrict__ x1,
                                                 const float* __restrict__ x2,
                                                 float* __restrict__ out)
{
    // [4 guard][wave0: 1040][4 guard][wave1: 1040][4 guard]
    __shared__ __align__(16) float lds[4 + WREG + 4 + WREG + 4];

    const int tid  = threadIdx.y * 16 + threadIdx.x;
    const int lane = tid & 63;
    const int w    = tid >> 6;             // wave 0/1
    const int tx   = lane & 15;            // x quad
    const int lr0  = lane >> 4;            // 0..3: row within wave

    // XCD-grouped swizzle: XCD m owns d-slice [4m,4m+4) -> hh re-reads L2-hit
    const int lin     = blockIdx.x;                    // 0..2559
    const int logical = (lin & 7) * 320 + (lin >> 3);
    const int bz   = logical % 10;
    const int rest = logical / 10;
    const int y0   = (rest & 7) * 8;
    const int d    = rest >> 3;
    const int b    = bz / 5;
    const int hi   = bz - b * 5;           // 0..4
    const int hh   = hi - 2;               // depth shift in [-2,2]
    const int y0w  = y0 + 4 * w;           // wave's first output row
    const int y    = y0w + lr0;
    const int x    = tx * 4;
    const int zd   = d - hh;
    const bool zok = (zd >= 0) && (zd < D_);

    // staging sources: slot A = tile rows 0..3, slot B = rows 4..7
    const float* x2b = x2 + (size_t)b * CDHW_ + (size_t)(zok ? zd : 0) * HW_;
    const int q   = tx;
    const int grA = y0w - 2 + lr0;                     // [-2, 61]
    const int grB = y0w + 2 + lr0;                     // [2, 67]
    const bool vA = zok && (grA >= 0);
    const bool vB = zok && (grB < H_);
    const float* pA = vA ? (x2b + grA * W_ + 4 * q) : g_zero;
    const float* pB = vB ? (x2b + grB * W_ + 4 * q) : g_zero;
    const int sA = vA ? DHW_ : 0;
    const int sB = vB ? DHW_ : 0;

    const int wbase = 4 + w * (WREG + 4);
    const int woA   = RSTRIDE * lr0 + 4 * q;           // write offs, rows 0..3
    const int woB   = woA + 4 * RSTRIDE;               // rows 4..7
    const int rdb   = RSTRIDE * lr0 + x;               // read base (row y-2)

    const float* p1 = x1 + (size_t)b * CDHW_ + (size_t)d * HW_ + (y * W_ + x);

    // dead-channel output base (16 zero channels per hi, spread over loop)
    float* obz = out + (size_t)b * NCH * DHW_ + (size_t)(23 + hi * 16) * DHW_
                     + (size_t)d * HW_ + (y * W_ + x);
    const float4 zero4 = make_float4(0.f, 0.f, 0.f, 0.f);

    // ---- preamble: issue groups 0 and 1; stage slab 0 into buf0
    float4 vA0 = *(const float4*)pA;       // group 0
    float4 vB0 = *(const float4*)pB;
    float4 a0  = *(const float4*)p1;
    pA += sA; pB += sB;                    // -> slab 1
    float4 rA1 = *(const float4*)pA;       // group 1 (held for iter 0's write)
    float4 rB1 = *(const float4*)pB;
    float4 a1  = *(const float4*)(p1 + DHW_);
    pA += sA; pB += sB;                    // -> slab 2

    {
        float* w0 = lds + wbase;           // buf 0
        w0[woA + 0] = vA0.x; w0[woA + 1] = vA0.y;
        w0[woA + 2] = vA0.z; w0[woA + 3] = vA0.w;
        w0[woB + 0] = vB0.x; w0[woB + 1] = vB0.y;
        w0[woB + 2] = vB0.z; w0[woB + 3] = vB0.w;
    }
    lds_fence();                           // writes visible before iter-0 reads

    float acc[9][4];
#pragma unroll
    for (int k = 0; k < 9; ++k)
#pragma unroll
        for (int j = 0; j < 4; ++j) acc[k][j] = 0.f;

    const bool lo_edge = (tx == 0);
    const bool hi_edge = (tx == 15);

#pragma unroll 2
    for (int c = 0; c < C_; ++c) {
        // 1. issue group c+2 (x2 slab c+2 -> regs, x1 slab c+2 -> na)
        float4 nA = *(const float4*)pA;
        float4 nB = *(const float4*)pB;
        float4 na = *(const float4*)(p1 + (size_t)((c + 2) & 63) * DHW_);
        if (c < 61) { pA += sA; pB += sB; }   // last real group is 63 (at c=61)

        // 2. compute slab c from buf[c&1] (conflict-free scalar reads)
        const float* Bb = lds + wbase + (c & 1) * TBUF + rdb;
        const float4 a = a0;
        float k0A0, k0A1, k0B0, k0B1;
#pragma unroll
        for (int k = 0; k < 5; ++k) {      // tile rows lr0..lr0+4 = y-2..y+2
            const int ro = RSTRIDE * k;
            const float cA0 = Bb[ro + 2];                 // cols x+2,x+3
            const float cA1 = Bb[ro + 3];
            float cB0 = Bb[ro + 4];                       // cols x+4,x+5
            float cB1 = Bb[ro + 5];
            cB0 = hi_edge ? 0.f : cB0;     // cols 64,65 don't exist
            cB1 = hi_edge ? 0.f : cB1;
            if (k == 0) { k0A0 = cA0; k0A1 = cA1; k0B0 = cB0; k0B1 = cB1; }
            const int ai = 4 - k;
            acc[ai][0] += a.x * cA0;
            acc[ai][1] += a.y * cA1;
            acc[ai][2] += a.z * cB0;
            acc[ai][3] += a.w * cB1;
        }
        {                                  // row part: tile row lr0 = y-2
            float rl0 = Bb[-2];                           // cols x-2,x-1
            float rl1 = Bb[-1];
            const float rl2 = Bb[0];                      // cols x,x+1
            const float rl3 = Bb[1];
            rl0 = lo_edge ? 0.f : rl0;     // cols -2,-1 don't exist
            rl1 = lo_edge ? 0.f : rl1;
            const float r8[8] = {rl0, rl1, rl2, rl3, k0A0, k0A1, k0B0, k0B1};
#pragma unroll
            for (int s = 1; s <= 4; ++s) { // voxel x+v uses r8[4+v-s]
                const int ai = s + 4;
                acc[ai][0] += a.x * r8[4 - s];
                acc[ai][1] += a.y * r8[5 - s];
                acc[ai][2] += a.z * r8[6 - s];
                acc[ai][3] += a.w * r8[7 - s];
            }
        }

        // 3. stage slab c+1 (loaded 1 iter ago -> ~1.5 iters latency cover)
        //    into buf[(c+1)&1]; conflict-free scalar writes, then FENCE so
        //    iter c+1's reads cannot pass these writes.
        {
            float* wd = lds + wbase + ((c + 1) & 1) * TBUF;
            wd[woA + 0] = rA1.x; wd[woA + 1] = rA1.y;
            wd[woA + 2] = rA1.z; wd[woA + 3] = rA1.w;
            wd[woB + 0] = rB1.x; wd[woB + 1] = rB1.y;
            wd[woB + 2] = rB1.z; wd[woB + 3] = rB1.w;
        }
        lds_fence();

        // 4. rotate pipeline registers
        rA1 = nA; rB1 = nB;
        a0 = a1; a1 = na;

        // 5. spread the 16 dead-channel zero stores across the loop
        if ((c & 3) == 0)
            *(float4*)(obz + (size_t)(c >> 2) * DHW_) = zero4;
    }

    // ---- epilogue: 9 live channels
    float* ob = out + (size_t)b * NCH * DHW_ + (size_t)d * HW_ + (y * W_ + x);
    const float inv = 1.0f / 125.0f;
#pragma unroll
    for (int k = 0; k < 9; ++k) {
        const int s = k - 4;
        int ch = 5 * s + hh;
        ch = (ch % NCH + NCH) % NCH;
        float4 v;
        v.x = acc[k][0] * inv;
        v.y = acc[k][1] * inv;
        v.z = acc[k][2] * inv;
        v.w = acc[k][3] * inv;
        *(float4*)(ob + (size_t)ch * DHW_) = v;
    }
}

extern "C" void kernel_launch(void* const* d_in, const int* in_sizes, int n_in,
                              void* d_out, int out_size, void* d_ws, size_t ws_size,
                              hipStream_t stream) {
    const float* x1 = (const float*)d_in[0];
    const float* x2 = (const float*)d_in[1];
    float* out = (float*)d_out;
    // 2560 blocks x 2 waves = 20 waves/CU, all resident
    cv_all<<<dim3(2560, 1, 1), dim3(16, 8, 1), 0, stream>>>(x1, x2, out);
}

// Round 3
// 267.169 us; speedup vs baseline: 1.4058x; 1.4058x over previous
//
#include <hip/hip_runtime.h>

// (B,C,D,H,W) = (2,64,32,64,64), R=2, NCH=125
#define B_ 2
#define C_ 64
#define D_ 32
#define H_ 64
#define W_ 64
#define NCH 125
#define HW_ 4096
#define DHW_ 131072
#define CDHW_ 8388608

// x2 tile per wave: 8 rows x 64 dwords, UNPADDED row-major = exactly the
// global_load_lds "uniform base + lane*16B" layout. 3 buffers (distance-2
// between DMA-write and the ds_reads of the same buffer). 4-dword guards
// front/back absorb the +-2-col halo reads of edge lanes (values masked).
// NOTE (R1/R2 lesson): the stride-64 layout has an 8-way read bank conflict,
// but it is hidden under HBM-boundness at 20 waves/CU; the conflict-free
// reg-staged rewrite (stride 65 + fences) regressed 114->219 us. Keep DMA.
#define TROWS 8
#define TBUF (TROWS * W_)          // 512 dwords per buffer
#define WREG (3 * TBUF)            // per-wave region (3 buffers)

typedef float f32x4 __attribute__((ext_vector_type(4)));

__device__ __attribute__((aligned(16))) const float g_zero[4] = {0.f, 0.f, 0.f, 0.f};

__device__ __forceinline__ void glds16(const float* g, float* l) {
    __builtin_amdgcn_global_load_lds(
        (const __attribute__((address_space(1))) void*)g,
        (__attribute__((address_space(3))) void*)l, 16, 0, 0);
}

// Output is write-once, never re-read: non-temporal (no-allocate) stores keep
// the 131 MB write stream out of L2/L3 so the 134 MB of inputs stay
// L3-resident across the 5x hh reuse (R2 counters: FETCH 300 MB vs 134 MB
// compulsory = L3 thrash from the write stream).
__device__ __forceinline__ void nt_store4(float* p, float a, float b,
                                          float c, float d) {
    f32x4 v = {a, b, c, d};
    __builtin_nontemporal_store(v, (f32x4*)p);
}

// Live offsets form an L: s=i+j in [-4..4], last-write winner is
//   s<=0 -> (i,j)=(s+2,-2): rows y-2..y+2, cols x+2..x+5  (acc[4-k])
//   s>=0 -> (i,j)=(2,s-2) : row y-2, cols x+2-s           (acc[s+4])
// ch=(5s+h) mod 125 -> live {0..22}u{103..124}; 23..102 identically zero.
__global__ __launch_bounds__(128, 5) void cv_all(const float* __restrict__ x1,
                                                 const float* __restrict__ x2,
                                                 float* __restrict__ out)
{
    __shared__ __align__(16) float lds[4 + 2 * WREG + 4];

    const int tid  = threadIdx.y * 16 + threadIdx.x;
    const int lane = tid & 63;
    const int w    = tid >> 6;             // wave 0/1
    const int tx   = lane & 15;            // x quad
    const int lr0  = lane >> 4;            // 0..3: row within wave

    // XCD-grouped swizzle: XCD m owns d-slice [4m,4m+4) -> hh re-reads L2-hit
    const int lin     = blockIdx.x;                    // 0..2559
    const int logical = (lin & 7) * 320 + (lin >> 3);
    const int bz   = logical % 10;
    const int rest = logical / 10;
    const int y0   = (rest & 7) * 8;
    const int d    = rest >> 3;
    const int b    = bz / 5;
    const int hi   = bz - b * 5;           // 0..4
    const int hh   = hi - 2;               // depth shift in [-2,2]
    const int y0w  = y0 + 4 * w;           // wave's first output row
    const int y    = y0w + lr0;
    const int x    = tx * 4;
    const int zd   = d - hh;
    const bool zok = (zd >= 0) && (zd < D_);

    // staging sources: slot A = tile rows 0..3, slot B = rows 4..7
    const float* x2b = x2 + (size_t)b * CDHW_ + (size_t)(zok ? zd : 0) * HW_;
    const int q   = lane & 15;
    const int grA = y0w - 2 + (lane >> 4);             // [-2, 61]
    const int grB = y0w + 2 + (lane >> 4);             // [2, 67]
    const bool vA = zok && (grA >= 0);
    const bool vB = zok && (grB < H_);
    const float* pA = vA ? (x2b + grA * W_ + 4 * q) : g_zero;
    const float* pB = vB ? (x2b + grB * W_ + 4 * q) : g_zero;
    const int sA = vA ? DHW_ : 0;
    const int sB = vB ? DHW_ : 0;

    const int wbase = 4 + w * WREG;
    const float* p1 = x1 + (size_t)b * CDHW_ + (size_t)d * HW_ + (y * W_ + x);

    // dead-channel output base (16 zero channels per hi, spread over loop)
    float* obz = out + (size_t)b * NCH * DHW_ + (size_t)(23 + hi * 16) * DHW_
                     + (size_t)d * HW_ + (y * W_ + x);

    // ---- preamble: DMA slab 0 -> buf0; x1 slab 0 -> a0
    glds16(pA, lds + wbase);
    glds16(pB, lds + wbase + TBUF / 2);
    float4 a0 = *(const float4*)p1;
    pA += sA; pB += sB;                    // -> slab 1

    float acc[9][4];
#pragma unroll
    for (int k = 0; k < 9; ++k)
#pragma unroll
        for (int j = 0; j < 4; ++j) acc[k][j] = 0.f;

    const bool lo_edge = (tx == 0);
    const bool hi_edge = (tx == 15);

#pragma unroll 2
    for (int c = 0; c < C_; ++c) {
        // 1. DMA slab c+1 -> buf (c+1)%3 (at c=63: re-DMA slab 63, harmless)
        float* dst = lds + wbase + ((c + 1) % 3) * TBUF;
        glds16(pA, dst);
        glds16(pB, dst + TBUF / 2);
        // 2. x1 slab c+1 (wraps to 0 at tail, harmless in-bounds load)
        float4 a1 = *(const float4*)(p1 + (size_t)((c + 1) & 63) * DHW_);
        if (c < 62) { pA += sA; pB += sB; }

        // 3. gate: allow this iter's 3 VMEM in flight; require buf(c) + a0 done
        asm volatile("s_waitcnt vmcnt(3)" ::: "memory");

        // 4. compute c from buf c%3
        const float* Bb = lds + wbase + (c % 3) * TBUF;
        const float4 a = a0;
        float2 k0A, k0B;
#pragma unroll
        for (int k = 0; k < 5; ++k) {      // tile rows lr0..lr0+4 = y-2..y+2
            const float* pr = Bb + (lr0 + k) * W_ + x;
            const float2 cA = *(const float2*)(pr + 2);   // cols x+2,x+3
            float2 cB = *(const float2*)(pr + 4);         // cols x+4,x+5
            cB.x = hi_edge ? 0.f : cB.x;   // cols 64,65 don't exist
            cB.y = hi_edge ? 0.f : cB.y;
            if (k == 0) { k0A = cA; k0B = cB; }
            const int ai = 4 - k;
            acc[ai][0] += a.x * cA.x;
            acc[ai][1] += a.y * cA.y;
            acc[ai][2] += a.z * cB.x;
            acc[ai][3] += a.w * cB.y;
        }
        {                                  // row part: tile row lr0 = y-2
            const float* pr = Bb + lr0 * W_ + x;
            float2 rlA = *(const float2*)(pr - 2);        // cols x-2,x-1
            const float2 rlB = *(const float2*)(pr);      // cols x,x+1
            rlA.x = lo_edge ? 0.f : rlA.x; // cols -2,-1 don't exist
            rlA.y = lo_edge ? 0.f : rlA.y;
            const float r8[8] = {rlA.x, rlA.y, rlB.x, rlB.y,
                                 k0A.x, k0A.y, k0B.x, k0B.y};
#pragma unroll
            for (int s = 1; s <= 4; ++s) { // voxel x+v uses r8[4+v-s]
                const int ai = s + 4;
                acc[ai][0] += a.x * r8[4 - s];
                acc[ai][1] += a.y * r8[5 - s];
                acc[ai][2] += a.z * r8[6 - s];
                acc[ai][3] += a.w * r8[7 - s];
            }
        }
        a0 = a1;

        // 5. spread the 16 dead-channel zero stores across the loop (nt)
        if ((c & 3) == 0)
            nt_store4(obz + (size_t)(c >> 2) * DHW_, 0.f, 0.f, 0.f, 0.f);
    }

    // ---- epilogue: 9 live channels (nt stores)
    float* ob = out + (size_t)b * NCH * DHW_ + (size_t)d * HW_ + (y * W_ + x);
    const float inv = 1.0f / 125.0f;
#pragma unroll
    for (int k = 0; k < 9; ++k) {
        const int s = k - 4;
        int ch = 5 * s + hh;
        ch = (ch % NCH + NCH) % NCH;
        nt_store4(ob + (size_t)ch * DHW_,
                  acc[k][0] * inv, acc[k][1] * inv,
                  acc[k][2] * inv, acc[k][3] * inv);
    }
}

extern "C" void kernel_launch(void* const* d_in, const int* in_sizes, int n_in,
                              void* d_out, int out_size, void* d_ws, size_t ws_size,
                              hipStream_t stream) {
    const float* x1 = (const float*)d_in[0];
    const float* x2 = (const float*)d_in[1];
    float* out = (float*)d_out;
    // 2560 blocks x 2 waves = 20 waves/CU, all resident
    cv_all<<<dim3(2560, 1, 1), dim3(16, 8, 1), 0, stream>>>(x1, x2, out);
}